// Round 10
// baseline (262.240 us; speedup 1.0000x reference)
//
#include <hip/hip_runtime.h>
#include <cstdint>

// AdaptiveNet: x[16384,1024] -> fc1(4096)+sigmoid -> grouped(512 g of 8)+sigmoid -> fc3(256)
// R10: operand-swapped fp8 core: gemm1 116us (MfmaUtil 54%), total 233.5us. BEST.
// R12: dbuf@256thr: REGRESSED (64KB -> 8 waves/CU; schedule right, waves wrong).
// R13: 128x256 tile: REGRESSED (232 regs -> 2 blocks/CU).
// R14: K-phase rotation: NEUTRAL (changes data order, not barrier timing; lockstep
//     is a stable equilibrium of identical periods + shared L2 path).
//     Model: per-wave duty 58% = measured MfmaUtil; waves stall together.
// R15: 8-wave (512thr) 128x128 block + dbuf prefetch = R12's schedule with R9's
//     wave count (R9's failure was the scaled-MFMA spill, not geometry).
//     16 waves/CU (4/SIMD) + stage(t+1) issued before compute(t); barrier drain
//     lands after ~1240cyc MFMA cover vs ~600-900cyc L2 latency. One barrier/K-step
//     (T3 2-phase recipe; race-checked). Core/epilogue formulas byte-identical
//     to R10; only wave partition (wn=(wave&3)*32, acc[2][4]) and chunk counts.

#define B_ROWS 16384
#define DIN 1024
#define H1  4096
#define H2  512
#define DOUT 256
#define TILE 128
#define TM3 64         // gemm3 M-tile (R11)
#define BK 64          // bf16 core (gemm3)
#define BK1 128        // fp8 core (gemm1)
#define LBUF (TILE * BK1)       // 16384 B per LDS buffer per matrix
#define INV_W1SCALE 0.015625f   // 1/64
#define CVT_BLOCKS 2048

#define NX4  (B_ROWS * DIN / 4)   // 4194304
#define NW14 (H1 * DIN / 4)       // 1048576
#define NW34 (DOUT * H2 / 4)      // 32768

typedef __bf16 bf16x8 __attribute__((ext_vector_type(8)));
typedef float f32x4 __attribute__((ext_vector_type(4)));

__device__ __forceinline__ unsigned short f2bf(float f) {
    union { float f; uint32_t u; } v; v.f = f;
    uint32_t u = v.u;
    u += 0x7FFFu + ((u >> 16) & 1u);   // round-to-nearest-even
    return (unsigned short)(u >> 16);
}

__device__ __forceinline__ float sigmoidf_fast(float x) {
    return 1.0f / (1.0f + __expf(-x));
}

// x -> fp8 (x1), W1 -> fp8 (x64), W3 -> bf16. Grid-stride over all three regions.
__global__ __launch_bounds__(256) void cvt3_kernel(
    const float* __restrict__ x, const float* __restrict__ w1,
    const float* __restrict__ w3, unsigned int* __restrict__ xo,
    unsigned int* __restrict__ w1o, unsigned short* __restrict__ w3o) {
    const int TOT = NX4 + NW14 + NW34;
    for (int i = blockIdx.x * 256 + threadIdx.x; i < TOT; i += CVT_BLOCKS * 256) {
        if (i < NX4) {
            float4 v = ((const float4*)x)[i];
            unsigned int p = 0;
            p = __builtin_amdgcn_cvt_pk_fp8_f32(v.x, v.y, p, false);
            p = __builtin_amdgcn_cvt_pk_fp8_f32(v.z, v.w, p, true);
            xo[i] = p;
        } else if (i < NX4 + NW14) {
            int j = i - NX4;
            float4 v = ((const float4*)w1)[j];
            unsigned int p = 0;
            p = __builtin_amdgcn_cvt_pk_fp8_f32(v.x * 64.0f, v.y * 64.0f, p, false);
            p = __builtin_amdgcn_cvt_pk_fp8_f32(v.z * 64.0f, v.w * 64.0f, p, true);
            w1o[j] = p;
        } else {
            int j = i - NX4 - NW14;
            float4 v = ((const float4*)w3)[j];
            ushort4 o;
            o.x = f2bf(v.x); o.y = f2bf(v.y); o.z = f2bf(v.z); o.w = f2bf(v.w);
            ((ushort4*)w3o)[j] = o;
        }
    }
}

__device__ __forceinline__ void load_lds16(const void* g, void* l) {
    __builtin_amdgcn_global_load_lds(
        (const __attribute__((address_space(1))) void*)g,
        (__attribute__((address_space(3))) void*)l, 16, 0, 0);
}

// ---------------- fp8 core, BK1=128, tile 128x128, 8 waves + dbuf (gemm1) ----------------
// LDS row = 128 fp8 = 128B = 8 chunks of 16B, chunk slots rotated by (row&7).
// A/B-frag (16x16x32 fp8): lane(q=l>>4,m=l&15) holds 8 consecutive fp8 at k=q*8
// within each k32 sub-chunk s; byte addr = row*128 + slot(2s+(q>>1))*16 + (q&1)*8.
// MFMA called as mfma(W1frag, Xfrag): D[row=h-col (q*4+i)][col=batch (m16)].
// Wave grid 2(M)x4(N): per-wave 64 rows x 32 cols, acc[2][4] (t=W1 16-blk, u=X 16-blk).
__global__ __launch_bounds__(512, 4) void gemm1_fused(
    const unsigned char* __restrict__ Xq,    // [16384,1024] fp8
    const unsigned char* __restrict__ W1q,   // [4096,1024]  fp8 (N,K), x64
    const float* __restrict__ b1,            // [4096]
    const float* __restrict__ W2,            // [512*8] flat; W2[g][s] = W2[gn]
    const float* __restrict__ b2,            // [512]
    unsigned short* __restrict__ X2) {       // [16384,512] bf16
    __shared__ __attribute__((aligned(16))) unsigned char lsA[2 * LBUF];  // 32KB
    __shared__ __attribute__((aligned(16))) unsigned char lsB[2 * LBUF];  // 32KB
    const int tid = threadIdx.x, lane = tid & 63, wave = tid >> 6;
    const int wm = (wave >> 2) * 64;      // 2 wave-rows of 64 (X rows)
    const int wn = (wave & 3) * 32;       // 4 wave-cols of 32 (W1 cols)

    // XCD-aware decode (R4): xcd owns a 512-col W1 slice (L2-resident)
    const int bid = blockIdx.x;
    const int xcd = bid & 7;
    const int local = bid >> 3;
    const int n0 = (xcd * 4 + (local & 3)) * TILE;
    const int a0 = (local >> 2) * TILE;

    const int q = lane >> 4, m16 = lane & 15;

    // staging: 2 chunks of 1KB per matrix per wave; chunk = 8 rows x 128B
    int gA[2], gB[2], lo[2];
#pragma unroll
    for (int i = 0; i < 2; ++i) {
        const int ch = wave * 2 + i;                 // 0..15
        const int r  = ch * 8 + (lane >> 3);
        const int kc = ((lane & 7) - (lane >> 3)) & 7;
        gA[i] = (a0 + r) * DIN + kc * 16;
        gB[i] = (n0 + r) * DIN + kc * 16;
        lo[i] = ch * 1024;
    }
    // fragment offsets: rowbase + slotoff (rotation = row&7 = m16&7)
    int rowA[4], rowB[2], so[4];
#pragma unroll
    for (int u = 0; u < 4; ++u)
        rowA[u] = (wm + u * 16 + m16) * BK1 + (q & 1) * 8;
#pragma unroll
    for (int t = 0; t < 2; ++t)
        rowB[t] = (wn + t * 16 + m16) * BK1 + (q & 1) * 8;
#pragma unroll
    for (int s = 0; s < 4; ++s)
        so[s] = ((s * 2 + (q >> 1) + (m16 & 7)) & 7) * 16;

    // acc[t][u]: t = W1 16-block (h cols, 2), u = X 16-block (batch rows, 4)
    f32x4 acc[2][4];
#pragma unroll
    for (int r = 0; r < 2; ++r)
#pragma unroll
        for (int c = 0; c < 4; ++c) acc[r][c] = (f32x4)0.0f;

    // prologue: stage tile 0 into buffer 0, drain at barrier
#pragma unroll
    for (int i = 0; i < 2; ++i) {
        load_lds16(Xq + gA[i], lsA + lo[i]);
        load_lds16(W1q + gB[i], lsB + lo[i]);
    }
    __syncthreads();

    int cur = 0;
    for (int kt = 0; kt < DIN / BK1; ++kt) {
        // issue stage of tile kt+1 into the other buffer; ~1240cyc of MFMA below covers it
        if (kt < DIN / BK1 - 1) {
            const int k0 = (kt + 1) * BK1;
            const int nb = (cur ^ 1) * LBUF;
#pragma unroll
            for (int i = 0; i < 2; ++i) {
                load_lds16(Xq + gA[i] + k0, lsA + nb + lo[i]);
                load_lds16(W1q + gB[i] + k0, lsB + nb + lo[i]);
            }
        }
        const unsigned char* bA = lsA + cur * LBUF;
        const unsigned char* bB = lsB + cur * LBUF;
#pragma unroll
        for (int s = 0; s < 4; ++s) {
            long fw[2], fx[4];
#pragma unroll
            for (int t = 0; t < 2; ++t) fw[t] = *(const long*)(bB + rowB[t] + so[s]);
#pragma unroll
            for (int u = 0; u < 4; ++u) fx[u] = *(const long*)(bA + rowA[u] + so[s]);
#pragma unroll
            for (int t = 0; t < 2; ++t)
#pragma unroll
                for (int u = 0; u < 4; ++u)
                    acc[t][u] = __builtin_amdgcn_mfma_f32_16x16x32_fp8_fp8(
                        fw[t], fx[u], acc[t][u], 0, 0, 0);
        }
        // one barrier per K-step: compute(kt) done for all waves (releases buf cur)
        // and each wave's prefetch drained (vmcnt(0) precedes s_barrier)
        __syncthreads();
        cur ^= 1;
    }

    // Epilogue. D[row = h-col offset (q*4+i)][col = batch (m16)]. acc is 64x true z1.
    // Group-of-8 reduce: 4 in-reg FMAs + one shfl_xor(16) joining q<->q^1.
#pragma unroll
    for (int t = 0; t < 2; ++t) {
        const int nb = n0 + wn + t * 16 + q * 4;      // this lane's first h col
        const float4 b1v = *(const float4*)(b1 + nb);
        const float4 w2v = *(const float4*)(W2 + nb);
        const int g = nb >> 3;                         // same for paired lanes q,q^1
        const float b2v = b2[g];
#pragma unroll
        for (int u = 0; u < 4; ++u) {
            const int gm = a0 + wm + u * 16 + m16;     // batch row
            const float h0 = sigmoidf_fast(acc[t][u][0] * INV_W1SCALE + b1v.x);
            const float h1 = sigmoidf_fast(acc[t][u][1] * INV_W1SCALE + b1v.y);
            const float h2 = sigmoidf_fast(acc[t][u][2] * INV_W1SCALE + b1v.z);
            const float h3 = sigmoidf_fast(acc[t][u][3] * INV_W1SCALE + b1v.w);
            float v = h0 * w2v.x + h1 * w2v.y + h2 * w2v.z + h3 * w2v.w;
            v += __shfl_xor(v, 16, 64);
            if ((q & 1) == 0)
                X2[gm * H2 + g] = f2bf(sigmoidf_fast(v + b2v));
        }
    }
}

// ---------------- bf16 core, BK=64, M-tile 64 (gemm3, R11) ----------------
// Chunk = 8 rows x 128B, rotation by row&7. A = 8 chunks (2/wave), B = 16 (4/wave).
// Wave grid 2x2: per-wave output 32x64, acc[2][4].
__global__ __launch_bounds__(256, 2) void gemm3_kernel(
    const unsigned short* __restrict__ X2,   // [16384,512] bf16
    const unsigned short* __restrict__ W3b,  // [256,512] bf16 (N,K)
    const float* __restrict__ b3,            // [256]
    float* __restrict__ Out) {               // [16384,256] f32
    __shared__ __attribute__((aligned(16))) unsigned short lsA[TM3 * BK];    // 8KB
    __shared__ __attribute__((aligned(16))) unsigned short lsB[TILE * BK];   // 16KB
    const int tid = threadIdx.x, lane = tid & 63, wave = tid >> 6;
    const int wm = (wave >> 1) * 32, wn = (wave & 1) * 64;
    const int m0 = blockIdx.y * TM3;
    const int n0 = blockIdx.x * TILE;
    const int q = lane >> 4, m16 = lane & 15;

    // staging: A 2 chunks/wave (ch 0..7), B 4 chunks/wave (ch 0..15)
    int gA[2], loA[2], gB[4], loB[4];
#pragma unroll
    for (int i = 0; i < 2; ++i) {
        const int ch = wave * 2 + i;
        const int r  = ch * 8 + (lane >> 3);
        const int kc = ((lane & 7) - (lane >> 3)) & 7;
        gA[i]  = (m0 + r) * H2 + kc * 8;
        loA[i] = ch * 512;
    }
#pragma unroll
    for (int i = 0; i < 4; ++i) {
        const int ch = wave * 4 + i;
        const int r  = ch * 8 + (lane >> 3);
        const int kc = ((lane & 7) - (lane >> 3)) & 7;
        gB[i]  = (n0 + r) * H2 + kc * 8;
        loB[i] = ch * 512;
    }
    int ra[2][2], rb[2][4];
#pragma unroll
    for (int h = 0; h < 2; ++h) {
        const int s = ((h * 4 + q + (m16 & 7)) & 7) * 8;
#pragma unroll
        for (int t = 0; t < 2; ++t) ra[h][t] = (wm + t * 16 + m16) * BK + s;
#pragma unroll
        for (int t = 0; t < 4; ++t) rb[h][t] = (wn + t * 16 + m16) * BK + s;
    }

    f32x4 acc[2][4];
#pragma unroll
    for (int r = 0; r < 2; ++r)
#pragma unroll
        for (int c = 0; c < 4; ++c) acc[r][c] = (f32x4)0.0f;

    for (int kt = 0; kt < H2 / BK; ++kt) {
        __syncthreads();
        const int k0 = kt * BK;
#pragma unroll
        for (int i = 0; i < 2; ++i) load_lds16(X2 + gA[i] + k0, lsA + loA[i]);
#pragma unroll
        for (int i = 0; i < 4; ++i) load_lds16(W3b + gB[i] + k0, lsB + loB[i]);
        __syncthreads();
#pragma unroll
        for (int h = 0; h < 2; ++h) {
            bf16x8 af[2], bfr[4];
#pragma unroll
            for (int t = 0; t < 2; ++t) af[t]  = *(const bf16x8*)(lsA + ra[h][t]);
#pragma unroll
            for (int t = 0; t < 4; ++t) bfr[t] = *(const bf16x8*)(lsB + rb[h][t]);
#pragma unroll
            for (int r = 0; r < 2; ++r)
#pragma unroll
                for (int c = 0; c < 4; ++c)
                    acc[r][c] = __builtin_amdgcn_mfma_f32_16x16x32_bf16(
                        af[r], bfr[c], acc[r][c], 0, 0, 0);
        }
    }

    // Epilogue: col = lane&15 (n), row = q*4+i (m).
#pragma unroll
    for (int c = 0; c < 4; ++c) {
        const int gn = n0 + wn + c * 16 + m16;
        const float b3v = b3[gn];
#pragma unroll
        for (int r = 0; r < 2; ++r) {
#pragma unroll
            for (int i = 0; i < 4; ++i) {
                const int gm = m0 + wm + r * 16 + q * 4 + i;
                Out[gm * DOUT + gn] = acc[r][c][i] + b3v;
            }
        }
    }
}

extern "C" void kernel_launch(void* const* d_in, const int* in_sizes, int n_in,
                              void* d_out, int out_size, void* d_ws, size_t ws_size,
                              hipStream_t stream) {
    const float* x  = (const float*)d_in[0];
    const float* W1 = (const float*)d_in[1];
    const float* b1 = (const float*)d_in[2];
    const float* W2 = (const float*)d_in[3];
    const float* b2 = (const float*)d_in[4];
    const float* W3 = (const float*)d_in[5];
    const float* b3 = (const float*)d_in[6];
    float* out = (float*)d_out;

    char* ws = (char*)d_ws;
    unsigned char*  x_q   = (unsigned char*)ws;                          // 16,777,216 B
    unsigned char*  w1_q  = (unsigned char*)(ws + 16777216);             //  4,194,304 B
    unsigned short* w3_bf = (unsigned short*)(ws + 16777216 + 4194304);  //    262,144 B
    unsigned short* x2_bf = (unsigned short*)(ws + 16777216 + 4194304 + 262144); // 16,777,216 B

    // Conversions: grid-stride, 2048 blocks (G11)
    cvt3_kernel<<<CVT_BLOCKS, 256, 0, stream>>>(
        x, W1, W3, (unsigned int*)x_q, (unsigned int*)w1_q, w3_bf);

    // GEMM1 (fp8, 8-wave dbuf) + fused layer 2: 1-D grid, XCD-aware decode inside
    gemm1_fused<<<(B_ROWS / TILE) * (H1 / TILE), 512, 0, stream>>>(
        x_q, w1_q, b1, W2, b2, x2_bf);

    // GEMM3 (bf16): grid = (2, 256), 2 blocks/CU
    gemm3_kernel<<<dim3(DOUT / TILE, B_ROWS / TM3), 256, 0, stream>>>(
        x2_bf, w3_bf, b3, out);
}

// Round 11
// 239.721 us; speedup vs baseline: 1.0939x; 1.0939x over previous
//
#include <hip/hip_runtime.h>
#include <cstdint>

// AdaptiveNet: x[16384,1024] -> fc1(4096)+sigmoid -> grouped(512 g of 8)+sigmoid -> fc3(256)
// R10: operand-swapped fp8 core, 128x128/4-wave: gemm1 116us (MfmaUtil 54%), 233.5 BEST.
// R12/R15: dbuf (256thr & 512thr): both REGRESSED. dbuf lane dead.
// R13: 128x256/4-wave: REGRESSED (acc[8][4] -> 2 blk/CU, 8 waves/CU).
// R14: K-phase rotation: NEUTRAL (data order != barrier timing).
// R15 mechanism: 64x32 wave tile -> 0.75 LDS reads/MFMA (conflict cycles x1.5).
// R16: R13's 128x256 block with 8 WAVES (2Mx4N of 64x64): per-wave = R10 exactly
//     (acc[4][4], 0.5 reads/MFMA, 128 regs) -> 16 waves/CU = 2 blk x 8 = 4/SIMD.
//     Per CU per K-step: 1024 MFMA per 96KB staged vs R10's 768 (1.33x compute
//     per staged byte). FETCH should halve (16 n-tiles read X, not 32).
//     Single buffer, 2 barriers, verified formulas. Pre-commit: fail -> R11 revert.

#define B_ROWS 16384
#define DIN 1024
#define H1  4096
#define H2  512
#define DOUT 256
#define TILE 128
#define TN1 256        // gemm1 N-tile (R16)
#define TM3 64         // gemm3 M-tile (R11)
#define BK 64          // bf16 core (gemm3)
#define BK1 128        // fp8 core (gemm1)
#define INV_W1SCALE 0.015625f   // 1/64
#define CVT_BLOCKS 2048

#define NX4  (B_ROWS * DIN / 4)   // 4194304
#define NW14 (H1 * DIN / 4)       // 1048576
#define NW34 (DOUT * H2 / 4)      // 32768

typedef __bf16 bf16x8 __attribute__((ext_vector_type(8)));
typedef float f32x4 __attribute__((ext_vector_type(4)));

__device__ __forceinline__ unsigned short f2bf(float f) {
    union { float f; uint32_t u; } v; v.f = f;
    uint32_t u = v.u;
    u += 0x7FFFu + ((u >> 16) & 1u);   // round-to-nearest-even
    return (unsigned short)(u >> 16);
}

__device__ __forceinline__ float sigmoidf_fast(float x) {
    return 1.0f / (1.0f + __expf(-x));
}

// x -> fp8 (x1), W1 -> fp8 (x64), W3 -> bf16. Grid-stride over all three regions.
__global__ __launch_bounds__(256) void cvt3_kernel(
    const float* __restrict__ x, const float* __restrict__ w1,
    const float* __restrict__ w3, unsigned int* __restrict__ xo,
    unsigned int* __restrict__ w1o, unsigned short* __restrict__ w3o) {
    const int TOT = NX4 + NW14 + NW34;
    for (int i = blockIdx.x * 256 + threadIdx.x; i < TOT; i += CVT_BLOCKS * 256) {
        if (i < NX4) {
            float4 v = ((const float4*)x)[i];
            unsigned int p = 0;
            p = __builtin_amdgcn_cvt_pk_fp8_f32(v.x, v.y, p, false);
            p = __builtin_amdgcn_cvt_pk_fp8_f32(v.z, v.w, p, true);
            xo[i] = p;
        } else if (i < NX4 + NW14) {
            int j = i - NX4;
            float4 v = ((const float4*)w1)[j];
            unsigned int p = 0;
            p = __builtin_amdgcn_cvt_pk_fp8_f32(v.x * 64.0f, v.y * 64.0f, p, false);
            p = __builtin_amdgcn_cvt_pk_fp8_f32(v.z * 64.0f, v.w * 64.0f, p, true);
            w1o[j] = p;
        } else {
            int j = i - NX4 - NW14;
            float4 v = ((const float4*)w3)[j];
            ushort4 o;
            o.x = f2bf(v.x); o.y = f2bf(v.y); o.z = f2bf(v.z); o.w = f2bf(v.w);
            ((ushort4*)w3o)[j] = o;
        }
    }
}

__device__ __forceinline__ void load_lds16(const void* g, void* l) {
    __builtin_amdgcn_global_load_lds(
        (const __attribute__((address_space(1))) void*)g,
        (__attribute__((address_space(3))) void*)l, 16, 0, 0);
}

// ---------------- fp8 core, BK1=128, tile 128x256, 8 waves (gemm1, R16) ----------------
// LDS row = 128 fp8 = 128B = 8 chunks of 16B, chunk slots rotated by (row&7).
// A/B-frag (16x16x32 fp8): lane(q=l>>4,m=l&15) holds 8 consecutive fp8 at k=q*8
// within each k32 sub-chunk s; byte addr = row*128 + slot(2s+(q>>1))*16 + (q&1)*8.
// MFMA called as mfma(W1frag, Xfrag): D[row=h-col (q*4+i)][col=batch (m16)].
// Wave grid 2(M-rows of X)x4(N-cols of W1), each wave 64x64 = R10's tile.
__global__ __launch_bounds__(512, 2) void gemm1_fused(
    const unsigned char* __restrict__ Xq,    // [16384,1024] fp8
    const unsigned char* __restrict__ W1q,   // [4096,1024]  fp8 (N,K), x64
    const float* __restrict__ b1,            // [4096]
    const float* __restrict__ W2,            // [512*8] flat; W2[g][s] = W2[gn]
    const float* __restrict__ b2,            // [512]
    unsigned short* __restrict__ X2) {       // [16384,512] bf16
    __shared__ __attribute__((aligned(16))) unsigned char lsA[TILE * BK1];   // 16KB
    __shared__ __attribute__((aligned(16))) unsigned char lsB[TN1 * BK1];    // 32KB
    const int tid = threadIdx.x, lane = tid & 63, wave = tid >> 6;
    const int wm = (wave >> 2) * 64;      // 2 wave-rows of 64 (X rows)
    const int wn = (wave & 3) * 64;       // 4 wave-cols of 64 (W1 cols)

    // XCD-aware decode: 16 n-tiles of 256; each XCD owns 2 (512-col L2 slice)
    const int bid = blockIdx.x;
    const int xcd = bid & 7;
    const int local = bid >> 3;                   // 0..255
    const int n0 = (xcd * 2 + (local & 1)) * TN1;
    const int a0 = (local >> 1) * TILE;

    const int q = lane >> 4, m16 = lane & 15;

    // staging: chunk = 8 rows x 128B. A: 16 chunks (2/wave); B: 32 chunks (4/wave)
    int gA[2], loA[2], gB[4], loB[4];
#pragma unroll
    for (int i = 0; i < 2; ++i) {
        const int ch = wave * 2 + i;                 // 0..15
        const int r  = ch * 8 + (lane >> 3);
        const int kc = ((lane & 7) - (lane >> 3)) & 7;
        gA[i]  = (a0 + r) * DIN + kc * 16;
        loA[i] = ch * 1024;
    }
#pragma unroll
    for (int i = 0; i < 4; ++i) {
        const int ch = wave * 4 + i;                 // 0..31
        const int r  = ch * 8 + (lane >> 3);
        const int kc = ((lane & 7) - (lane >> 3)) & 7;
        gB[i]  = (n0 + r) * DIN + kc * 16;
        loB[i] = ch * 1024;
    }
    // fragment offsets: rowbase (t/u) + slotoff (s); rotation = row&7 = m16&7
    int rowA[4], rowB[4], so[4];
#pragma unroll
    for (int u = 0; u < 4; ++u)
        rowA[u] = (wm + u * 16 + m16) * BK1 + (q & 1) * 8;
#pragma unroll
    for (int t = 0; t < 4; ++t)
        rowB[t] = (wn + t * 16 + m16) * BK1 + (q & 1) * 8;
#pragma unroll
    for (int s = 0; s < 4; ++s)
        so[s] = ((s * 2 + (q >> 1) + (m16 & 7)) & 7) * 16;

    // acc[t][u]: t = W1 16-block (h cols), u = X 16-block (batch rows)
    f32x4 acc[4][4];
#pragma unroll
    for (int r = 0; r < 4; ++r)
#pragma unroll
        for (int c = 0; c < 4; ++c) acc[r][c] = (f32x4)0.0f;

    for (int kt = 0; kt < DIN / BK1; ++kt) {
        __syncthreads();
        const int k0 = kt * BK1;
#pragma unroll
        for (int i = 0; i < 2; ++i) load_lds16(Xq + gA[i] + k0, lsA + loA[i]);
#pragma unroll
        for (int i = 0; i < 4; ++i) load_lds16(W1q + gB[i] + k0, lsB + loB[i]);
        __syncthreads();
#pragma unroll
        for (int s = 0; s < 4; ++s) {
            long fw[4], fx[4];
#pragma unroll
            for (int t = 0; t < 4; ++t) fw[t] = *(const long*)(lsB + rowB[t] + so[s]);
#pragma unroll
            for (int u = 0; u < 4; ++u) fx[u] = *(const long*)(lsA + rowA[u] + so[s]);
#pragma unroll
            for (int t = 0; t < 4; ++t)
#pragma unroll
                for (int u = 0; u < 4; ++u)
                    acc[t][u] = __builtin_amdgcn_mfma_f32_16x16x32_fp8_fp8(
                        fw[t], fx[u], acc[t][u], 0, 0, 0);
        }
    }

    // Epilogue. D[row = h-col offset (q*4+i)][col = batch (m16)]. acc is 64x true z1.
    // Group-of-8 reduce: 4 in-reg FMAs + one shfl_xor(16) joining q<->q^1.
#pragma unroll
    for (int t = 0; t < 4; ++t) {
        const int nb = n0 + wn + t * 16 + q * 4;      // this lane's first h col
        const float4 b1v = *(const float4*)(b1 + nb);
        const float4 w2v = *(const float4*)(W2 + nb);
        const int g = nb >> 3;                         // same for paired lanes q,q^1
        const float b2v = b2[g];
#pragma unroll
        for (int u = 0; u < 4; ++u) {
            const int gm = a0 + wm + u * 16 + m16;     // batch row
            const float h0 = sigmoidf_fast(acc[t][u][0] * INV_W1SCALE + b1v.x);
            const float h1 = sigmoidf_fast(acc[t][u][1] * INV_W1SCALE + b1v.y);
            const float h2 = sigmoidf_fast(acc[t][u][2] * INV_W1SCALE + b1v.z);
            const float h3 = sigmoidf_fast(acc[t][u][3] * INV_W1SCALE + b1v.w);
            float v = h0 * w2v.x + h1 * w2v.y + h2 * w2v.z + h3 * w2v.w;
            v += __shfl_xor(v, 16, 64);
            if ((q & 1) == 0)
                X2[gm * H2 + g] = f2bf(sigmoidf_fast(v + b2v));
        }
    }
}

// ---------------- bf16 core, BK=64, M-tile 64 (gemm3, R11) ----------------
// Chunk = 8 rows x 128B, rotation by row&7. A = 8 chunks (2/wave), B = 16 (4/wave).
// Wave grid 2x2: per-wave output 32x64, acc[2][4].
__global__ __launch_bounds__(256, 2) void gemm3_kernel(
    const unsigned short* __restrict__ X2,   // [16384,512] bf16
    const unsigned short* __restrict__ W3b,  // [256,512] bf16 (N,K)
    const float* __restrict__ b3,            // [256]
    float* __restrict__ Out) {               // [16384,256] f32
    __shared__ __attribute__((aligned(16))) unsigned short lsA[TM3 * BK];    // 8KB
    __shared__ __attribute__((aligned(16))) unsigned short lsB[TILE * BK];   // 16KB
    const int tid = threadIdx.x, lane = tid & 63, wave = tid >> 6;
    const int wm = (wave >> 1) * 32, wn = (wave & 1) * 64;
    const int m0 = blockIdx.y * TM3;
    const int n0 = blockIdx.x * TILE;
    const int q = lane >> 4, m16 = lane & 15;

    // staging: A 2 chunks/wave (ch 0..7), B 4 chunks/wave (ch 0..15)
    int gA[2], loA[2], gB[4], loB[4];
#pragma unroll
    for (int i = 0; i < 2; ++i) {
        const int ch = wave * 2 + i;
        const int r  = ch * 8 + (lane >> 3);
        const int kc = ((lane & 7) - (lane >> 3)) & 7;
        gA[i]  = (m0 + r) * H2 + kc * 8;
        loA[i] = ch * 512;
    }
#pragma unroll
    for (int i = 0; i < 4; ++i) {
        const int ch = wave * 4 + i;
        const int r  = ch * 8 + (lane >> 3);
        const int kc = ((lane & 7) - (lane >> 3)) & 7;
        gB[i]  = (n0 + r) * H2 + kc * 8;
        loB[i] = ch * 512;
    }
    int ra[2][2], rb[2][4];
#pragma unroll
    for (int h = 0; h < 2; ++h) {
        const int s = ((h * 4 + q + (m16 & 7)) & 7) * 8;
#pragma unroll
        for (int t = 0; t < 2; ++t) ra[h][t] = (wm + t * 16 + m16) * BK + s;
#pragma unroll
        for (int t = 0; t < 4; ++t) rb[h][t] = (wn + t * 16 + m16) * BK + s;
    }

    f32x4 acc[2][4];
#pragma unroll
    for (int r = 0; r < 2; ++r)
#pragma unroll
        for (int c = 0; c < 4; ++c) acc[r][c] = (f32x4)0.0f;

    for (int kt = 0; kt < H2 / BK; ++kt) {
        __syncthreads();
        const int k0 = kt * BK;
#pragma unroll
        for (int i = 0; i < 2; ++i) load_lds16(X2 + gA[i] + k0, lsA + loA[i]);
#pragma unroll
        for (int i = 0; i < 4; ++i) load_lds16(W3b + gB[i] + k0, lsB + loB[i]);
        __syncthreads();
#pragma unroll
        for (int h = 0; h < 2; ++h) {
            bf16x8 af[2], bfr[4];
#pragma unroll
            for (int t = 0; t < 2; ++t) af[t]  = *(const bf16x8*)(lsA + ra[h][t]);
#pragma unroll
            for (int t = 0; t < 4; ++t) bfr[t] = *(const bf16x8*)(lsB + rb[h][t]);
#pragma unroll
            for (int r = 0; r < 2; ++r)
#pragma unroll
                for (int c = 0; c < 4; ++c)
                    acc[r][c] = __builtin_amdgcn_mfma_f32_16x16x32_bf16(
                        af[r], bfr[c], acc[r][c], 0, 0, 0);
        }
    }

    // Epilogue: col = lane&15 (n), row = q*4+i (m).
#pragma unroll
    for (int c = 0; c < 4; ++c) {
        const int gn = n0 + wn + c * 16 + m16;
        const float b3v = b3[gn];
#pragma unroll
        for (int r = 0; r < 2; ++r) {
#pragma unroll
            for (int i = 0; i < 4; ++i) {
                const int gm = m0 + wm + r * 16 + q * 4 + i;
                Out[gm * DOUT + gn] = acc[r][c][i] + b3v;
            }
        }
    }
}

extern "C" void kernel_launch(void* const* d_in, const int* in_sizes, int n_in,
                              void* d_out, int out_size, void* d_ws, size_t ws_size,
                              hipStream_t stream) {
    const float* x  = (const float*)d_in[0];
    const float* W1 = (const float*)d_in[1];
    const float* b1 = (const float*)d_in[2];
    const float* W2 = (const float*)d_in[3];
    const float* b2 = (const float*)d_in[4];
    const float* W3 = (const float*)d_in[5];
    const float* b3 = (const float*)d_in[6];
    float* out = (float*)d_out;

    char* ws = (char*)d_ws;
    unsigned char*  x_q   = (unsigned char*)ws;                          // 16,777,216 B
    unsigned char*  w1_q  = (unsigned char*)(ws + 16777216);             //  4,194,304 B
    unsigned short* w3_bf = (unsigned short*)(ws + 16777216 + 4194304);  //    262,144 B
    unsigned short* x2_bf = (unsigned short*)(ws + 16777216 + 4194304 + 262144); // 16,777,216 B

    // Conversions: grid-stride, 2048 blocks (G11)
    cvt3_kernel<<<CVT_BLOCKS, 256, 0, stream>>>(
        x, W1, W3, (unsigned int*)x_q, (unsigned int*)w1_q, w3_bf);

    // GEMM1 (fp8, 128x256 8-wave) + fused layer 2: 1-D grid, XCD-aware decode inside
    gemm1_fused<<<(B_ROWS / TILE) * (H1 / TN1), 512, 0, stream>>>(
        x_q, w1_q, b1, W2, b2, x2_bf);

    // GEMM3 (bf16): grid = (2, 256), 2 blocks/CU
    gemm3_kernel<<<dim3(DOUT / TILE, B_ROWS / TM3), 256, 0, stream>>>(
        x2_bf, w3_bf, b3, out);
}

// Round 12
// 233.079 us; speedup vs baseline: 1.1251x; 1.0285x over previous
//
#include <hip/hip_runtime.h>
#include <cstdint>

// AdaptiveNet: x[16384,1024] -> fc1(4096)+sigmoid -> grouped(512 g of 8)+sigmoid -> fc3(256)
// FINAL (R17 = R11 config, best measured 233.3us):
//   cvt3 (grid-stride 2048 blocks) -> gemm1_fused fp8 128x128/4-wave operand-swapped
//   (114-116us, MfmaUtil ~52%) -> gemm3 bf16 128x64 tiles.
// Session ledger:
//   R10 WIN: operand-swap epilogue (mfma(W1frag,Xfrag), h-cols on reg axis):
//       grouped reduce = 4 FMA + 1 shfl_xor vs 192 shfl. gemm1 164->116us.
//   R11 NEUTRAL: cvt3 grid-stride + gemm3 TM3=64 (tail is launch-gap dominated).
//   R6-R9 DEAD: mfma_scale K=128 acc lives in arch VGPRs -> spill or 1 blk/CU
//       at every geometry; inline-asm non-scaled form crashes the container.
//   R12/R15 DEAD: LDS dbuf prefetch (256thr & 512thr) - occupancy loss >= hiding;
//       __syncthreads drains prefetch (vmcnt(0) before s_barrier).
//   R13/R15/R16 DEAD: any tile != 128x128/4-wave/64x64-per-wave loses via regs
//       (R13: 2blk/CU), reuse ratio (R15: 0.75 reads/MFMA), or stage phase (R16).
//   R14 NEUTRAL: K-phase rotation (barrier timing, not data order, sets lockstep).
// Ceiling: 2-barrier structure at 52% MfmaUtil vs 67us MFMA floor; breaking it
// needs the 8-phase counted-vmcnt template (new sync structure, race-screen req'd).

#define B_ROWS 16384
#define DIN 1024
#define H1  4096
#define H2  512
#define DOUT 256
#define TILE 128
#define TM3 64         // gemm3 M-tile
#define BK 64          // bf16 core (gemm3)
#define BK1 128        // fp8 core (gemm1)
#define INV_W1SCALE 0.015625f   // 1/64
#define CVT_BLOCKS 2048

#define NX4  (B_ROWS * DIN / 4)   // 4194304
#define NW14 (H1 * DIN / 4)       // 1048576
#define NW34 (DOUT * H2 / 4)      // 32768

typedef __bf16 bf16x8 __attribute__((ext_vector_type(8)));
typedef float f32x4 __attribute__((ext_vector_type(4)));

__device__ __forceinline__ unsigned short f2bf(float f) {
    union { float f; uint32_t u; } v; v.f = f;
    uint32_t u = v.u;
    u += 0x7FFFu + ((u >> 16) & 1u);   // round-to-nearest-even
    return (unsigned short)(u >> 16);
}

__device__ __forceinline__ float sigmoidf_fast(float x) {
    return 1.0f / (1.0f + __expf(-x));
}

// x -> fp8 (x1), W1 -> fp8 (x64), W3 -> bf16. Grid-stride over all three regions.
__global__ __launch_bounds__(256) void cvt3_kernel(
    const float* __restrict__ x, const float* __restrict__ w1,
    const float* __restrict__ w3, unsigned int* __restrict__ xo,
    unsigned int* __restrict__ w1o, unsigned short* __restrict__ w3o) {
    const int TOT = NX4 + NW14 + NW34;
    for (int i = blockIdx.x * 256 + threadIdx.x; i < TOT; i += CVT_BLOCKS * 256) {
        if (i < NX4) {
            float4 v = ((const float4*)x)[i];
            unsigned int p = 0;
            p = __builtin_amdgcn_cvt_pk_fp8_f32(v.x, v.y, p, false);
            p = __builtin_amdgcn_cvt_pk_fp8_f32(v.z, v.w, p, true);
            xo[i] = p;
        } else if (i < NX4 + NW14) {
            int j = i - NX4;
            float4 v = ((const float4*)w1)[j];
            unsigned int p = 0;
            p = __builtin_amdgcn_cvt_pk_fp8_f32(v.x * 64.0f, v.y * 64.0f, p, false);
            p = __builtin_amdgcn_cvt_pk_fp8_f32(v.z * 64.0f, v.w * 64.0f, p, true);
            w1o[j] = p;
        } else {
            int j = i - NX4 - NW14;
            float4 v = ((const float4*)w3)[j];
            ushort4 o;
            o.x = f2bf(v.x); o.y = f2bf(v.y); o.z = f2bf(v.z); o.w = f2bf(v.w);
            ((ushort4*)w3o)[j] = o;
        }
    }
}

__device__ __forceinline__ void load_lds16(const void* g, void* l) {
    __builtin_amdgcn_global_load_lds(
        (const __attribute__((address_space(1))) void*)g,
        (__attribute__((address_space(3))) void*)l, 16, 0, 0);
}

// ---------------- fp8 core, BK1=128, tile 128x128 (gemm1, R10-verified) ----------------
// LDS row = 128 fp8 = 128B = 8 chunks of 16B, chunk slots rotated by (row&7).
// A/B-frag (16x16x32 fp8): lane(q=l>>4,m=l&15) holds 8 consecutive fp8 at k=q*8
// within each k32 sub-chunk s; byte addr = row*128 + slot(2s+(q>>1))*16 + (q&1)*8.
// MFMA called as mfma(W1frag, Xfrag): D[row=h-col (q*4+i)][col=batch (m16)].
__global__ __launch_bounds__(256, 2) void gemm1_fused(
    const unsigned char* __restrict__ Xq,    // [16384,1024] fp8
    const unsigned char* __restrict__ W1q,   // [4096,1024]  fp8 (N,K), x64
    const float* __restrict__ b1,            // [4096]
    const float* __restrict__ W2,            // [512*8] flat; W2[g][s] = W2[gn]
    const float* __restrict__ b2,            // [512]
    unsigned short* __restrict__ X2) {       // [16384,512] bf16
    __shared__ __attribute__((aligned(16))) unsigned char lsA[TILE * BK1];
    __shared__ __attribute__((aligned(16))) unsigned char lsB[TILE * BK1];
    const int tid = threadIdx.x, lane = tid & 63, wave = tid >> 6;
    const int wm = (wave >> 1) * 64, wn = (wave & 1) * 64;

    // XCD-aware decode (R4): xcd owns a 512-col W1 slice (L2-resident)
    const int bid = blockIdx.x;
    const int xcd = bid & 7;
    const int local = bid >> 3;
    const int n0 = (xcd * 4 + (local & 3)) * TILE;
    const int a0 = (local >> 2) * TILE;

    const int q = lane >> 4, m16 = lane & 15;

    // staging: 4 chunks of 1KB per matrix per wave; chunk = 8 rows x 128B
    int gA[4], gB[4], lo[4];
#pragma unroll
    for (int i = 0; i < 4; ++i) {
        const int ch = wave * 4 + i;
        const int r  = ch * 8 + (lane >> 3);
        const int kc = ((lane & 7) - (lane >> 3)) & 7;
        gA[i] = (a0 + r) * DIN + kc * 16;
        gB[i] = (n0 + r) * DIN + kc * 16;
        lo[i] = ch * 1024;
    }
    // fragment offsets: rowbase (t) + slotoff (s)
    int rowA[4], rowB[4], so[4];
#pragma unroll
    for (int t = 0; t < 4; ++t) {
        rowA[t] = (wm + t * 16 + m16) * BK1 + (q & 1) * 8;
        rowB[t] = (wn + t * 16 + m16) * BK1 + (q & 1) * 8;
    }
#pragma unroll
    for (int s = 0; s < 4; ++s)
        so[s] = ((s * 2 + (q >> 1) + (m16 & 7)) & 7) * 16;

    // acc[t][u]: t = W1 16-block (h cols), u = X 16-block (batch rows)
    f32x4 acc[4][4];
#pragma unroll
    for (int r = 0; r < 4; ++r)
#pragma unroll
        for (int c = 0; c < 4; ++c) acc[r][c] = (f32x4)0.0f;

    for (int kt = 0; kt < DIN / BK1; ++kt) {
        __syncthreads();
        const int k0 = kt * BK1;
#pragma unroll
        for (int i = 0; i < 4; ++i) {
            load_lds16(Xq + gA[i] + k0, lsA + lo[i]);
            load_lds16(W1q + gB[i] + k0, lsB + lo[i]);
        }
        __syncthreads();
#pragma unroll
        for (int s = 0; s < 4; ++s) {
            long fw[4], fx[4];
#pragma unroll
            for (int t = 0; t < 4; ++t) fw[t] = *(const long*)(lsB + rowB[t] + so[s]);
#pragma unroll
            for (int t = 0; t < 4; ++t) fx[t] = *(const long*)(lsA + rowA[t] + so[s]);
#pragma unroll
            for (int t = 0; t < 4; ++t)
#pragma unroll
                for (int u = 0; u < 4; ++u)
                    acc[t][u] = __builtin_amdgcn_mfma_f32_16x16x32_fp8_fp8(
                        fw[t], fx[u], acc[t][u], 0, 0, 0);
        }
    }

    // Epilogue. D[row = h-col offset (q*4+i)][col = batch (m16)]. acc is 64x true z1.
    // Group-of-8 reduce: 4 in-reg FMAs + one shfl_xor(16) joining q<->q^1.
#pragma unroll
    for (int t = 0; t < 4; ++t) {
        const int nb = n0 + wn + t * 16 + q * 4;      // this lane's first h col
        const float4 b1v = *(const float4*)(b1 + nb);
        const float4 w2v = *(const float4*)(W2 + nb);
        const int g = nb >> 3;                         // same for paired lanes q,q^1
        const float b2v = b2[g];
#pragma unroll
        for (int u = 0; u < 4; ++u) {
            const int gm = a0 + wm + u * 16 + m16;     // batch row
            const float h0 = sigmoidf_fast(acc[t][u][0] * INV_W1SCALE + b1v.x);
            const float h1 = sigmoidf_fast(acc[t][u][1] * INV_W1SCALE + b1v.y);
            const float h2 = sigmoidf_fast(acc[t][u][2] * INV_W1SCALE + b1v.z);
            const float h3 = sigmoidf_fast(acc[t][u][3] * INV_W1SCALE + b1v.w);
            float v = h0 * w2v.x + h1 * w2v.y + h2 * w2v.z + h3 * w2v.w;
            v += __shfl_xor(v, 16, 64);
            if ((q & 1) == 0)
                X2[gm * H2 + g] = f2bf(sigmoidf_fast(v + b2v));
        }
    }
}

// ---------------- bf16 core, BK=64, M-tile 64 (gemm3, R11) ----------------
// Chunk = 8 rows x 128B, rotation by row&7. A = 8 chunks (2/wave), B = 16 (4/wave).
// Wave grid 2x2: per-wave output 32x64, acc[2][4].
__global__ __launch_bounds__(256, 2) void gemm3_kernel(
    const unsigned short* __restrict__ X2,   // [16384,512] bf16
    const unsigned short* __restrict__ W3b,  // [256,512] bf16 (N,K)
    const float* __restrict__ b3,            // [256]
    float* __restrict__ Out) {               // [16384,256] f32
    __shared__ __attribute__((aligned(16))) unsigned short lsA[TM3 * BK];    // 8KB
    __shared__ __attribute__((aligned(16))) unsigned short lsB[TILE * BK];   // 16KB
    const int tid = threadIdx.x, lane = tid & 63, wave = tid >> 6;
    const int wm = (wave >> 1) * 32, wn = (wave & 1) * 64;
    const int m0 = blockIdx.y * TM3;
    const int n0 = blockIdx.x * TILE;
    const int q = lane >> 4, m16 = lane & 15;

    // staging: A 2 chunks/wave (ch 0..7), B 4 chunks/wave (ch 0..15)
    int gA[2], loA[2], gB[4], loB[4];
#pragma unroll
    for (int i = 0; i < 2; ++i) {
        const int ch = wave * 2 + i;
        const int r  = ch * 8 + (lane >> 3);
        const int kc = ((lane & 7) - (lane >> 3)) & 7;
        gA[i]  = (m0 + r) * H2 + kc * 8;
        loA[i] = ch * 512;
    }
#pragma unroll
    for (int i = 0; i < 4; ++i) {
        const int ch = wave * 4 + i;
        const int r  = ch * 8 + (lane >> 3);
        const int kc = ((lane & 7) - (lane >> 3)) & 7;
        gB[i]  = (n0 + r) * H2 + kc * 8;
        loB[i] = ch * 512;
    }
    int ra[2][2], rb[2][4];
#pragma unroll
    for (int h = 0; h < 2; ++h) {
        const int s = ((h * 4 + q + (m16 & 7)) & 7) * 8;
#pragma unroll
        for (int t = 0; t < 2; ++t) ra[h][t] = (wm + t * 16 + m16) * BK + s;
#pragma unroll
        for (int t = 0; t < 4; ++t) rb[h][t] = (wn + t * 16 + m16) * BK + s;
    }

    f32x4 acc[2][4];
#pragma unroll
    for (int r = 0; r < 2; ++r)
#pragma unroll
        for (int c = 0; c < 4; ++c) acc[r][c] = (f32x4)0.0f;

    for (int kt = 0; kt < H2 / BK; ++kt) {
        __syncthreads();
        const int k0 = kt * BK;
#pragma unroll
        for (int i = 0; i < 2; ++i) load_lds16(X2 + gA[i] + k0, lsA + loA[i]);
#pragma unroll
        for (int i = 0; i < 4; ++i) load_lds16(W3b + gB[i] + k0, lsB + loB[i]);
        __syncthreads();
#pragma unroll
        for (int h = 0; h < 2; ++h) {
            bf16x8 af[2], bfr[4];
#pragma unroll
            for (int t = 0; t < 2; ++t) af[t]  = *(const bf16x8*)(lsA + ra[h][t]);
#pragma unroll
            for (int t = 0; t < 4; ++t) bfr[t] = *(const bf16x8*)(lsB + rb[h][t]);
#pragma unroll
            for (int r = 0; r < 2; ++r)
#pragma unroll
                for (int c = 0; c < 4; ++c)
                    acc[r][c] = __builtin_amdgcn_mfma_f32_16x16x32_bf16(
                        af[r], bfr[c], acc[r][c], 0, 0, 0);
        }
    }

    // Epilogue: col = lane&15 (n), row = q*4+i (m).
#pragma unroll
    for (int c = 0; c < 4; ++c) {
        const int gn = n0 + wn + c * 16 + m16;
        const float b3v = b3[gn];
#pragma unroll
        for (int r = 0; r < 2; ++r) {
#pragma unroll
            for (int i = 0; i < 4; ++i) {
                const int gm = m0 + wm + r * 16 + q * 4 + i;
                Out[gm * DOUT + gn] = acc[r][c][i] + b3v;
            }
        }
    }
}

extern "C" void kernel_launch(void* const* d_in, const int* in_sizes, int n_in,
                              void* d_out, int out_size, void* d_ws, size_t ws_size,
                              hipStream_t stream) {
    const float* x  = (const float*)d_in[0];
    const float* W1 = (const float*)d_in[1];
    const float* b1 = (const float*)d_in[2];
    const float* W2 = (const float*)d_in[3];
    const float* b2 = (const float*)d_in[4];
    const float* W3 = (const float*)d_in[5];
    const float* b3 = (const float*)d_in[6];
    float* out = (float*)d_out;

    char* ws = (char*)d_ws;
    unsigned char*  x_q   = (unsigned char*)ws;                          // 16,777,216 B
    unsigned char*  w1_q  = (unsigned char*)(ws + 16777216);             //  4,194,304 B
    unsigned short* w3_bf = (unsigned short*)(ws + 16777216 + 4194304);  //    262,144 B
    unsigned short* x2_bf = (unsigned short*)(ws + 16777216 + 4194304 + 262144); // 16,777,216 B

    // Conversions: grid-stride, 2048 blocks (G11)
    cvt3_kernel<<<CVT_BLOCKS, 256, 0, stream>>>(
        x, W1, W3, (unsigned int*)x_q, (unsigned int*)w1_q, w3_bf);

    // GEMM1 (fp8) + fused layer 2: 1-D grid, XCD-aware decode inside
    gemm1_fused<<<(B_ROWS / TILE) * (H1 / TILE), 256, 0, stream>>>(
        x_q, w1_q, b1, W2, b2, x2_bf);

    // GEMM3 (bf16): grid = (2, 256), 2 blocks/CU
    gemm3_kernel<<<dim3(DOUT / TILE, B_ROWS / TM3), 256, 0, stream>>>(
        x2_bf, w3_bf, b3, out);
}